// Round 5
// baseline (335.271 us; speedup 1.0000x reference)
//
#include <hip/hip_runtime.h>

// KGCN forward, MI355X. 8 waves/block (512 thr), one wave per batch element.
// LDS holds ONLY: W (swizzled float4 chunks), rel^T (stride 65), and the
// 9 pre-activation rows per element. Everything else (ids, scores, attention
// weights, ue) lives in registers and moves via readlane/bpermute.
// 51,456 B LDS -> 3 blocks/CU; __launch_bounds__(512,6) pins VGPR <= ~84
// -> 24 waves/CU for latency hiding.

namespace {

constexpr int kDim      = 64;
constexpr int kNN       = 8;
constexpr int kNumEnt   = 100000;
constexpr int kItemInKG = 20000;
constexpr int kElems    = 8;    // batch elements (waves) per block
constexpr int kVecs     = 9;    // pre0 + 8x pre1 rows per element
constexpr int kRelChunks = 976; // 61 rel rows * 16 float4 chunks

__device__ __forceinline__ float fast_sigmoid(float x) {
  return 1.0f / (1.0f + __expf(-x));
}
__device__ __forceinline__ float fast_tanh(float x) {
  return 2.0f / (1.0f + __expf(-2.0f * x)) - 1.0f;
}
// literal/uniform-lane broadcast: v_readlane -> SGPR (free as VOP3 src)
__device__ __forceinline__ float readlane_f(float v, int lane) {
  return __int_as_float(__builtin_amdgcn_readlane(__float_as_int(v), lane));
}

__global__ void __launch_bounds__(kElems * 64, 6)
kgcn_kernel(const int* __restrict__ u, const int* __restrict__ v,
            const float* __restrict__ usr_emb, const float* __restrict__ item_emb,
            const float* __restrict__ ent_emb, const float* __restrict__ rel_emb,
            const float* __restrict__ W, const float* __restrict__ bias,
            const int* __restrict__ adj_ent, const int* __restrict__ adj_rel,
            float* __restrict__ out)
{
  const int tid = threadIdx.x;
  const int wv  = tid >> 6;
  const int ln  = tid & 63;
  const int b   = blockIdx.x * kElems + wv;

  __shared__ float4 s_w4[kDim * 16];                       // 16,384 B
  __shared__ float  s_relt[kDim * 65];                     // 16,640 B
  __shared__ __align__(16) float s_pre[kElems][kVecs][kDim]; // 18,432 B

  // ---- staging loads (coalesced float4), writes deferred ----
  const float4* W4 = reinterpret_cast<const float4*>(W);
  const float4* R4 = reinterpret_cast<const float4*>(rel_emb);
  const float4 wst0 = W4[tid];
  const float4 wst1 = W4[512 + tid];
  const float4 rst0 = R4[tid];   // tid < 512 < 976: always in range
  const float4 rst1 = (512 + tid < kRelChunks) ? R4[512 + tid]
                                               : make_float4(0.f, 0.f, 0.f, 0.f);

  // ---- adjacency chain (registers + cross-lane only) ----
  const int   uid = u[b];
  const int   vid = v[b];
  const float ue  = usr_emb[(size_t)uid * kDim + ln];
  const float ev0 = item_emb[(size_t)vid * kDim + ln];
  const int   e0  = (vid >= kItemInKG) ? kNumEnt : vid;    // pad entity

  int e1v = 0, r1v = 0;
  if (ln < kNN) {
    e1v = adj_ent[(size_t)e0 * kNN + ln];
    r1v = adj_rel[(size_t)e0 * kNN + ln];
  }
  const int parent = __shfl(e1v, ln >> 3, 64);   // lanes 0..7 are sources
  const int e2v    = adj_ent[(size_t)parent * kNN + (ln & 7)];
  const int r2v    = adj_rel[(size_t)parent * kNN + (ln & 7)];

  // ---- staging writes (2-way banks at worst = free) ----
  {
    int id = tid, row = id >> 4, col = id & 15;
    s_w4[(row << 4) | (col & 8) | ((col ^ row) & 7)] = wst0;
    id = 512 + tid; row = id >> 4; col = id & 15;
    s_w4[(row << 4) | (col & 8) | ((col ^ row) & 7)] = wst1;
  }
  {
    int id = tid, r = id >> 4, c = (id & 15) << 2;
    s_relt[(c + 0) * 65 + r] = rst0.x;
    s_relt[(c + 1) * 65 + r] = rst0.y;
    s_relt[(c + 2) * 65 + r] = rst0.z;
    s_relt[(c + 3) * 65 + r] = rst0.w;
    id = 512 + tid; r = id >> 4; c = (id & 15) << 2;   // rows 61..63 get zeros
    s_relt[(c + 0) * 65 + r] = rst1.x;
    s_relt[(c + 1) * 65 + r] = rst1.y;
    s_relt[(c + 2) * 65 + r] = rst1.z;
    s_relt[(c + 3) * 65 + r] = rst1.w;
  }

  // ---- early gathers: hop-1 rows + hop-2 row 0 (latency covered by
  // barrier + t-pass + softmax). ids via readlane -> SGPR saddr loads.
  float ev1r[kNN];
  #pragma unroll
  for (int m = 0; m < kNN; ++m)
    ev1r[m] = ent_emb[(size_t)__builtin_amdgcn_readlane(e1v, m) * kDim + ln];
  float g[kNN];
  #pragma unroll
  for (int n = 0; n < kNN; ++n)
    g[n] = ent_emb[(size_t)__builtin_amdgcn_readlane(e2v, n) * kDim + ln];

  __syncthreads();   // staging visible

  // ---- t[r] = dot(ue, rel_emb[r]), lane = r. One vaddr + imm offsets;
  // banks (k + ln) % 32: conflict-free. ue[k] via readlane (SGPR operand).
  float t;
  {
    float a0 = 0.f, a1 = 0.f, a2 = 0.f, a3 = 0.f;
    const float* relc = &s_relt[ln];
    #pragma unroll
    for (int k = 0; k < kDim; k += 4) {
      a0 = fmaf(readlane_f(ue, k + 0), relc[(k + 0) * 65], a0);
      a1 = fmaf(readlane_f(ue, k + 1), relc[(k + 1) * 65], a1);
      a2 = fmaf(readlane_f(ue, k + 2), relc[(k + 2) * 65], a2);
      a3 = fmaf(readlane_f(ue, k + 3), relc[(k + 3) * 65], a3);
    }
    t = (a0 + a1) + (a2 + a3);
  }

  // ---- softmaxes: scores via bpermute lookup of t; 8-lane groups ----
  float w2v;   // hop-2 weight for pair (ln>>3, ln&7)
  {
    const float s2 = __shfl(t, r2v, 64);
    float mx = s2;
    #pragma unroll
    for (int m = 1; m <= 4; m <<= 1) mx = fmaxf(mx, __shfl_xor(mx, m, 64));
    const float e = __expf(s2 - mx);
    float sm = e;
    #pragma unroll
    for (int m = 1; m <= 4; m <<= 1) sm += __shfl_xor(sm, m, 64);
    w2v = e / sm;
  }
  float w0v;   // hop-0 weight, valid on lanes 0..7 (reused for iter-1)
  {
    const float s0 = __shfl(t, r1v, 64);
    float mx = s0;
    #pragma unroll
    for (int m = 1; m <= 4; m <<= 1) mx = fmaxf(mx, __shfl_xor(mx, m, 64));
    w0v = __expf(s0 - mx);
    float sm = w0v;
    #pragma unroll
    for (int m = 1; m <= 4; m <<= 1) sm += __shfl_xor(sm, m, 64);
    w0v /= sm;
  }

  // ---- aggregation (lane = dim) ----
  {
    float agg = 0.f;
    #pragma unroll
    for (int n = 0; n < kNN; ++n)
      agg = fmaf(readlane_f(w0v, n), ev1r[n], agg);
    s_pre[wv][0][ln] = ev0 + agg;
  }
  // rows 1..8, software-pipelined gathers (row m+1 in flight over row m math)
  #pragma unroll
  for (int m = 0; m < kNN; ++m) {
    float gn[kNN];
    if (m < kNN - 1) {
      #pragma unroll
      for (int n = 0; n < kNN; ++n)
        gn[n] = ent_emb[(size_t)__builtin_amdgcn_readlane(e2v, (m + 1) * kNN + n) * kDim + ln];
    }
    float acc = 0.f;
    #pragma unroll
    for (int n = 0; n < kNN; ++n)
      acc = fmaf(readlane_f(w2v, m * kNN + n), g[n], acc);
    s_pre[wv][1 + m][ln] = ev1r[m] + acc;
    if (m < kNN - 1) {
      #pragma unroll
      for (int n = 0; n < kNN; ++n) g[n] = gn[n];
    }
  }

  // ---- matvecs, 3 rows per W pass. W chunk read at (ln<<4)|q is ONE vaddr
  // + imm q*16 (zero addr VALU); its content is W[ln] chunk c=(q&8)|((q^ln)&7),
  // so the p-rows are read at chunk c (8-way-broadcast, conflict-free);
  // 3 p-reads share a vaddr via +256B immediates. FMA order over c is a
  // permutation -> sum unchanged (fp reassociation within tolerance).
  const float bln = bias[ln];
  float h[kVecs];
  #pragma unroll
  for (int g3 = 0; g3 < 3; ++g3) {
    const float* p0 = &s_pre[wv][g3 * 3 + 0][0];
    float acc0 = 0.f, acc1 = 0.f, acc2 = 0.f;
    #pragma unroll
    for (int q = 0; q < 16; ++q) {
      const int    c4 = ((q & 8) | ((q ^ ln) & 7)) << 2;
      const float4 wk = s_w4[(ln << 4) | q];
      const float4 pa = *reinterpret_cast<const float4*>(p0 + c4);
      const float4 pb = *reinterpret_cast<const float4*>(p0 + 64 + c4);
      const float4 pc = *reinterpret_cast<const float4*>(p0 + 128 + c4);
      acc0 = fmaf(wk.x, pa.x, acc0); acc0 = fmaf(wk.y, pa.y, acc0);
      acc0 = fmaf(wk.z, pa.z, acc0); acc0 = fmaf(wk.w, pa.w, acc0);
      acc1 = fmaf(wk.x, pb.x, acc1); acc1 = fmaf(wk.y, pb.y, acc1);
      acc1 = fmaf(wk.z, pb.z, acc1); acc1 = fmaf(wk.w, pb.w, acc1);
      acc2 = fmaf(wk.x, pc.x, acc2); acc2 = fmaf(wk.y, pc.y, acc2);
      acc2 = fmaf(wk.z, pc.z, acc2); acc2 = fmaf(wk.w, pc.w, acc2);
    }
    h[g3 * 3 + 0] = fast_sigmoid(acc0 + bln);   // iter 0 -> sigmoid
    h[g3 * 3 + 1] = fast_sigmoid(acc1 + bln);
    h[g3 * 3 + 2] = fast_sigmoid(acc2 + bln);
  }

  // ---- iter-1 hop-0 (same ue, same rels -> reuse w0) ----
  {
    float pre = h[0];
    #pragma unroll
    for (int n = 0; n < kNN; ++n)
      pre = fmaf(readlane_f(w0v, n), h[1 + n], pre);
    s_pre[wv][0][ln] = pre;   // in-order DS per wave: no barrier needed
  }

  // ---- final matvec + tanh + user dot ----
  {
    const float* p0 = &s_pre[wv][0][0];
    float acc = 0.f;
    #pragma unroll
    for (int q = 0; q < 16; ++q) {
      const int    c4 = ((q & 8) | ((q ^ ln) & 7)) << 2;
      const float4 wk = s_w4[(ln << 4) | q];
      const float4 pa = *reinterpret_cast<const float4*>(p0 + c4);
      acc = fmaf(wk.x, pa.x, acc); acc = fmaf(wk.y, pa.y, acc);
      acc = fmaf(wk.z, pa.z, acc); acc = fmaf(wk.w, pa.w, acc);
    }
    const float item = fast_tanh(acc + bln);
    float tt = ue * item;
    #pragma unroll
    for (int off = 32; off > 0; off >>= 1)
      tt += __shfl_xor(tt, off, 64);
    if (ln == 0) out[b] = fast_sigmoid(tt);
  }
}

}  // namespace

extern "C" void kernel_launch(void* const* d_in, const int* in_sizes, int n_in,
                              void* d_out, int out_size, void* d_ws, size_t ws_size,
                              hipStream_t stream) {
  const int*   u        = (const int*)d_in[0];
  const int*   v        = (const int*)d_in[1];
  const float* usr_emb  = (const float*)d_in[2];
  const float* item_emb = (const float*)d_in[3];
  const float* ent_emb  = (const float*)d_in[4];
  const float* rel_emb  = (const float*)d_in[5];
  const float* W        = (const float*)d_in[6];
  const float* bias     = (const float*)d_in[7];
  const int*   adj_ent  = (const int*)d_in[8];
  const int*   adj_rel  = (const int*)d_in[9];
  float*       out      = (float*)d_out;

  const int B = in_sizes[0];   // 16384, divisible by kElems=8
  dim3 grid(B / kElems), block(kElems * 64);
  hipLaunchKernelGGL(kgcn_kernel, grid, block, 0, stream,
                     u, v, usr_emb, item_emb, ent_emb, rel_emb, W, bias,
                     adj_ent, adj_rel, out);
}

// Round 6
// 94.269 us; speedup vs baseline: 3.5565x; 3.5565x over previous
//
#include <hip/hip_runtime.h>

// KGCN forward, MI355X. 8 waves/block (512 thr), one wave per batch element.
// R6 = R4 skeleton + three evidence-driven fixes:
//  - W and rel tables in LDS with 68-float row stride (272B): bank =
//    4*(row+chunk) % 32 -> conflict-free per-lane-row ds_read_b128.
//  - ids/scores/attention weights register-resident (readlane/bpermute);
//    LDS = 53,248 B -> 3 blocks/CU = 24 waves/CU.
//  - no forced VGPR bound, no manual prefetch arrays (R5 spill lesson).

namespace {

constexpr int kDim      = 64;
constexpr int kNN       = 8;
constexpr int kNumEnt   = 100000;
constexpr int kItemInKG = 20000;
constexpr int kElems    = 8;     // batch elements (waves) per block
constexpr int kVecs     = 9;     // pre0 + 8x pre1 rows per element
constexpr int kPad      = 68;    // row stride in floats (272 B)
constexpr int kRelChunks = 976;  // 61 rel rows * 16 float4 chunks

__device__ __forceinline__ float fast_sigmoid(float x) {
  return 1.0f / (1.0f + __expf(-x));
}
__device__ __forceinline__ float fast_tanh(float x) {
  return 2.0f / (1.0f + __expf(-2.0f * x)) - 1.0f;
}
__device__ __forceinline__ float readlane_f(float v, int lane) {
  return __int_as_float(__builtin_amdgcn_readlane(__float_as_int(v), lane));
}

__global__ void __launch_bounds__(kElems * 64)
kgcn_kernel(const int* __restrict__ u, const int* __restrict__ v,
            const float* __restrict__ usr_emb, const float* __restrict__ item_emb,
            const float* __restrict__ ent_emb, const float* __restrict__ rel_emb,
            const float* __restrict__ W, const float* __restrict__ bias,
            const int* __restrict__ adj_ent, const int* __restrict__ adj_rel,
            float* __restrict__ out)
{
  const int tid = threadIdx.x;
  const int wv  = tid >> 6;
  const int ln  = tid & 63;
  const int b   = blockIdx.x * kElems + wv;

  __shared__ __align__(16) float s_w[kDim * kPad];   // 17,408 B, W[row][68]
  __shared__ __align__(16) float s_rel[kDim * kPad]; // 17,408 B, rel[row][68]
  __shared__ __align__(16) float s_pre[kElems][kVecs][kDim]; // 18,432 B

  // ---- staging loads (coalesced float4) ----
  const float4* W4 = reinterpret_cast<const float4*>(W);
  const float4* R4 = reinterpret_cast<const float4*>(rel_emb);
  const float4 wst0 = W4[tid];
  const float4 wst1 = W4[512 + tid];
  const float4 rst0 = R4[tid];                       // 512 < 976: in range
  const float4 rst1 = (512 + tid < kRelChunks) ? R4[512 + tid]
                                               : make_float4(0.f, 0.f, 0.f, 0.f);

  // ---- adjacency chain (registers + cross-lane only) ----
  const int   uid = u[b];
  const int   vid = v[b];
  const float ue  = usr_emb[(size_t)uid * kDim + ln];
  const float ev0 = item_emb[(size_t)vid * kDim + ln];
  const int   e0  = (vid >= kItemInKG) ? kNumEnt : vid;   // pad entity

  int e1v = 0, r1v = 0;
  if (ln < kNN) {
    e1v = adj_ent[(size_t)e0 * kNN + ln];
    r1v = adj_rel[(size_t)e0 * kNN + ln];
  }
  const int parent = __shfl(e1v, ln >> 3, 64);   // sources are lanes 0..7
  const int e2v    = adj_ent[(size_t)parent * kNN + (ln & 7)];
  const int r2v    = adj_rel[(size_t)parent * kNN + (ln & 7)];

  // ---- staging writes: chunk id -> row id>>4, chunk id&15, stride 68 ----
  {
    int id = tid;
    *reinterpret_cast<float4*>(&s_w[(id >> 4) * kPad + ((id & 15) << 2)]) = wst0;
    id = 512 + tid;
    *reinterpret_cast<float4*>(&s_w[(id >> 4) * kPad + ((id & 15) << 2)]) = wst1;
    id = tid;
    *reinterpret_cast<float4*>(&s_rel[(id >> 4) * kPad + ((id & 15) << 2)]) = rst0;
    id = 512 + tid;   // rows 61..63 get zeros (never indexed by r<61 anyway)
    *reinterpret_cast<float4*>(&s_rel[(id >> 4) * kPad + ((id & 15) << 2)]) = rst1;
  }

  // ---- hop-1 embedding gathers (8 rows, ids wave-uniform via readlane) ----
  float ev1r[kNN];
  #pragma unroll
  for (int m = 0; m < kNN; ++m)
    ev1r[m] = ent_emb[(size_t)__builtin_amdgcn_readlane(e1v, m) * kDim + ln];

  __syncthreads();   // staging visible

  // ---- t[r] = dot(ue, rel_emb[r]), lane = r: 16 conflict-free b128 reads,
  // ue[k] broadcast via readlane (SGPR operand on the FMA).
  float t;
  {
    const float* relr = &s_rel[ln * kPad];
    float a0 = 0.f, a1 = 0.f, a2 = 0.f, a3 = 0.f;
    #pragma unroll
    for (int q = 0; q < 16; ++q) {
      const float4 r4 = *reinterpret_cast<const float4*>(relr + (q << 2));
      a0 = fmaf(readlane_f(ue, 4 * q + 0), r4.x, a0);
      a1 = fmaf(readlane_f(ue, 4 * q + 1), r4.y, a1);
      a2 = fmaf(readlane_f(ue, 4 * q + 2), r4.z, a2);
      a3 = fmaf(readlane_f(ue, 4 * q + 3), r4.w, a3);
    }
    t = (a0 + a1) + (a2 + a3);
  }

  // ---- softmaxes: score = bpermute lookup of t; 8-lane groups {1,2,4} ----
  float w2v;   // hop-2 weight for pair (m = ln>>3, n = ln&7)
  {
    const float s2 = __shfl(t, r2v, 64);
    float mx = s2;
    #pragma unroll
    for (int m = 1; m <= 4; m <<= 1) mx = fmaxf(mx, __shfl_xor(mx, m, 64));
    const float e = __expf(s2 - mx);
    float sm = e;
    #pragma unroll
    for (int m = 1; m <= 4; m <<= 1) sm += __shfl_xor(sm, m, 64);
    w2v = e / sm;
  }
  float w0v;   // hop-0 weight, valid on lanes 0..7 (reused for iter-1)
  {
    const float s0 = __shfl(t, r1v, 64);
    float mx = s0;
    #pragma unroll
    for (int m = 1; m <= 4; m <<= 1) mx = fmaxf(mx, __shfl_xor(mx, m, 64));
    w0v = __expf(s0 - mx);
    float sm = w0v;
    #pragma unroll
    for (int m = 1; m <= 4; m <<= 1) sm += __shfl_xor(sm, m, 64);
    w0v /= sm;
  }

  // ---- aggregation (lane = dim) ----
  {
    float agg = 0.f;
    #pragma unroll
    for (int n = 0; n < kNN; ++n)
      agg = fmaf(readlane_f(w0v, n), ev1r[n], agg);
    s_pre[wv][0][ln] = ev0 + agg;
  }
  // rows 1..8: 8 gathers per row, unroll 2 (16 in flight max; occupancy
  // does the rest of the hiding -- no manual prefetch, R5 lesson).
  #pragma unroll 2
  for (int m = 0; m < kNN; ++m) {
    float acc = 0.f;
    #pragma unroll
    for (int n = 0; n < kNN; ++n) {
      const int e2u = __builtin_amdgcn_readlane(e2v, m * kNN + n);
      acc = fmaf(readlane_f(w2v, m * kNN + n),
                 ent_emb[(size_t)e2u * kDim + ln], acc);
    }
    s_pre[wv][1 + m][ln] = ev1r[m] + acc;
  }

  // ---- matvecs, 3 rows per W pass. Wreg chunk q = W[ln][4q..4q+3]
  // (natural order, conflict-free); p-chunks are 64-lane broadcasts and the
  // 3 rows share one vaddr via +256B immediates.
  const float bln = bias[ln];
  const float* wr = &s_w[ln * kPad];
  float h[kVecs];
  #pragma unroll
  for (int g3 = 0; g3 < 3; ++g3) {
    const float* p0 = &s_pre[wv][g3 * 3][0];
    float acc0 = 0.f, acc1 = 0.f, acc2 = 0.f;
    #pragma unroll
    for (int q = 0; q < 16; ++q) {
      const float4 wk = *reinterpret_cast<const float4*>(wr + (q << 2));
      const float4 pa = *reinterpret_cast<const float4*>(p0 + (q << 2));
      const float4 pb = *reinterpret_cast<const float4*>(p0 + 64 + (q << 2));
      const float4 pc = *reinterpret_cast<const float4*>(p0 + 128 + (q << 2));
      acc0 = fmaf(wk.x, pa.x, acc0); acc0 = fmaf(wk.y, pa.y, acc0);
      acc0 = fmaf(wk.z, pa.z, acc0); acc0 = fmaf(wk.w, pa.w, acc0);
      acc1 = fmaf(wk.x, pb.x, acc1); acc1 = fmaf(wk.y, pb.y, acc1);
      acc1 = fmaf(wk.z, pb.z, acc1); acc1 = fmaf(wk.w, pb.w, acc1);
      acc2 = fmaf(wk.x, pc.x, acc2); acc2 = fmaf(wk.y, pc.y, acc2);
      acc2 = fmaf(wk.z, pc.z, acc2); acc2 = fmaf(wk.w, pc.w, acc2);
    }
    h[g3 * 3 + 0] = fast_sigmoid(acc0 + bln);   // iter 0 -> sigmoid
    h[g3 * 3 + 1] = fast_sigmoid(acc1 + bln);
    h[g3 * 3 + 2] = fast_sigmoid(acc2 + bln);
  }

  // ---- iter-1 hop-0 (same ue, same rels -> reuse w0) ----
  {
    float pre = h[0];
    #pragma unroll
    for (int n = 0; n < kNN; ++n)
      pre = fmaf(readlane_f(w0v, n), h[1 + n], pre);
    s_pre[wv][0][ln] = pre;   // wave-internal DS ordering: no barrier needed
  }

  // ---- final matvec + tanh + user dot ----
  {
    const float* p0 = &s_pre[wv][0][0];
    float acc = 0.f;
    #pragma unroll
    for (int q = 0; q < 16; ++q) {
      const float4 wk = *reinterpret_cast<const float4*>(wr + (q << 2));
      const float4 pa = *reinterpret_cast<const float4*>(p0 + (q << 2));
      acc = fmaf(wk.x, pa.x, acc); acc = fmaf(wk.y, pa.y, acc);
      acc = fmaf(wk.z, pa.z, acc); acc = fmaf(wk.w, pa.w, acc);
    }
    const float item = fast_tanh(acc + bln);
    float tt = ue * item;
    #pragma unroll
    for (int off = 32; off > 0; off >>= 1)
      tt += __shfl_xor(tt, off, 64);
    if (ln == 0) out[b] = fast_sigmoid(tt);
  }
}

}  // namespace

extern "C" void kernel_launch(void* const* d_in, const int* in_sizes, int n_in,
                              void* d_out, int out_size, void* d_ws, size_t ws_size,
                              hipStream_t stream) {
  const int*   u        = (const int*)d_in[0];
  const int*   v        = (const int*)d_in[1];
  const float* usr_emb  = (const float*)d_in[2];
  const float* item_emb = (const float*)d_in[3];
  const float* ent_emb  = (const float*)d_in[4];
  const float* rel_emb  = (const float*)d_in[5];
  const float* W        = (const float*)d_in[6];
  const float* bias     = (const float*)d_in[7];
  const int*   adj_ent  = (const int*)d_in[8];
  const int*   adj_rel  = (const int*)d_in[9];
  float*       out      = (float*)d_out;

  const int B = in_sizes[0];   // 16384, divisible by kElems=8
  dim3 grid(B / kElems), block(kElems * 64);
  hipLaunchKernelGGL(kgcn_kernel, grid, block, 0, stream,
                     u, v, usr_emb, item_emb, ent_emb, rel_emb, W, bias,
                     adj_ent, adj_rel, out);
}

// Round 7
// 64.792 us; speedup vs baseline: 5.1746x; 1.4549x over previous
//
#include <hip/hip_runtime.h>

// KGCN forward, MI355X. 8 waves/block (512 thr), one wave per batch element.
// R7 = R4's measured-good skeleton + register-resident ids/scores:
//  - W staged once to LDS (chunk-XOR swizzle), register-cached per lane in
//    ONE 16-read pass (R6 lesson: repeated strided-row LDS reads are ~8-way
//    conflicted regardless of padding -- minimize their count).
//  - rel staged TRANSPOSED stride-65: t-pass is 64 ds_read_b32, 2-way = free.
//  - ids/scores/weights in registers (shfl/readlane); LDS = 51,456 B
//    -> 3 blocks/CU = 24 waves/CU.
//  - Wreg loaded AFTER aggregation (live-range separation, no forced bound).

namespace {

constexpr int kDim      = 64;
constexpr int kNN       = 8;
constexpr int kNumEnt   = 100000;
constexpr int kItemInKG = 20000;
constexpr int kElems    = 8;     // batch elements (waves) per block
constexpr int kVecs     = 9;     // pre0 + 8x pre1 rows per element
constexpr int kRelChunks = 976;  // 61 rel rows * 16 float4 chunks

__device__ __forceinline__ float fast_sigmoid(float x) {
  return 1.0f / (1.0f + __expf(-x));
}
__device__ __forceinline__ float fast_tanh(float x) {
  return 2.0f / (1.0f + __expf(-2.0f * x)) - 1.0f;
}
__device__ __forceinline__ float readlane_f(float v, int lane) {
  return __int_as_float(__builtin_amdgcn_readlane(__float_as_int(v), lane));
}

__global__ void __launch_bounds__(kElems * 64)
kgcn_kernel(const int* __restrict__ u, const int* __restrict__ v,
            const float* __restrict__ usr_emb, const float* __restrict__ item_emb,
            const float* __restrict__ ent_emb, const float* __restrict__ rel_emb,
            const float* __restrict__ W, const float* __restrict__ bias,
            const int* __restrict__ adj_ent, const int* __restrict__ adj_rel,
            float* __restrict__ out)
{
  const int tid = threadIdx.x;
  const int wv  = tid >> 6;
  const int ln  = tid & 63;
  const int b   = blockIdx.x * kElems + wv;

  __shared__ float4 s_w4[kDim * 16];                         // 16,384 B
  __shared__ float  s_relt[kDim * 65];                       // 16,640 B
  __shared__ __align__(16) float s_pre[kElems][kVecs][kDim]; // 18,432 B

  // ---- staging loads (coalesced float4) ----
  const float4* W4 = reinterpret_cast<const float4*>(W);
  const float4* R4 = reinterpret_cast<const float4*>(rel_emb);
  const float4 wst0 = W4[tid];
  const float4 wst1 = W4[512 + tid];
  const float4 rst0 = R4[tid];                   // 512 < 976: in range
  const float4 rst1 = (512 + tid < kRelChunks) ? R4[512 + tid]
                                               : make_float4(0.f, 0.f, 0.f, 0.f);

  // ---- adjacency chain (registers + cross-lane only) ----
  const int   uid = u[b];
  const int   vid = v[b];
  const float ue  = usr_emb[(size_t)uid * kDim + ln];
  const float ev0 = item_emb[(size_t)vid * kDim + ln];
  const int   e0  = (vid >= kItemInKG) ? kNumEnt : vid;   // pad entity

  int e1v = 0, r1v = 0;
  if (ln < kNN) {
    e1v = adj_ent[(size_t)e0 * kNN + ln];
    r1v = adj_rel[(size_t)e0 * kNN + ln];
  }
  const int parent = __shfl(e1v, ln >> 3, 64);   // sources are lanes 0..7
  const int e2v    = adj_ent[(size_t)parent * kNN + (ln & 7)];
  const int r2v    = adj_rel[(size_t)parent * kNN + (ln & 7)];

  // ---- staging writes ----
  {
    // W: chunk-XOR swizzle (position = (col&8)|((col^row)&7)); reading at
    // (k4&8)|((k4^ln)&7) later recovers natural chunk order (involution).
    int id = tid, row = id >> 4, col = id & 15;
    s_w4[(row << 4) | (col & 8) | ((col ^ row) & 7)] = wst0;
    id = 512 + tid; row = id >> 4; col = id & 15;
    s_w4[(row << 4) | (col & 8) | ((col ^ row) & 7)] = wst1;
  }
  {
    // rel transposed: s_relt[k*65 + r] = rel[r][k]; write banks 2-way = free.
    int id = tid, r = id >> 4, c = (id & 15) << 2;
    s_relt[(c + 0) * 65 + r] = rst0.x;
    s_relt[(c + 1) * 65 + r] = rst0.y;
    s_relt[(c + 2) * 65 + r] = rst0.z;
    s_relt[(c + 3) * 65 + r] = rst0.w;
    id = 512 + tid; r = id >> 4; c = (id & 15) << 2;  // rows 61..63: zeros
    s_relt[(c + 0) * 65 + r] = rst1.x;
    s_relt[(c + 1) * 65 + r] = rst1.y;
    s_relt[(c + 2) * 65 + r] = rst1.z;
    s_relt[(c + 3) * 65 + r] = rst1.w;
  }

  // ---- hop-1 embedding gathers (ids wave-uniform via readlane -> saddr) ----
  float ev1r[kNN];
  #pragma unroll
  for (int m = 0; m < kNN; ++m)
    ev1r[m] = ent_emb[(size_t)__builtin_amdgcn_readlane(e1v, m) * kDim + ln];

  __syncthreads();   // staging visible

  // ---- t[r] = dot(ue, rel_emb[r]), lane = r. Column reads (k+ln)%32 banks:
  // 2-way aliased = free. ue[k] broadcast via readlane (SGPR FMA operand).
  float t;
  {
    const float* relc = &s_relt[ln];
    float a0 = 0.f, a1 = 0.f, a2 = 0.f, a3 = 0.f;
    #pragma unroll
    for (int k = 0; k < kDim; k += 4) {
      a0 = fmaf(readlane_f(ue, k + 0), relc[(k + 0) * 65], a0);
      a1 = fmaf(readlane_f(ue, k + 1), relc[(k + 1) * 65], a1);
      a2 = fmaf(readlane_f(ue, k + 2), relc[(k + 2) * 65], a2);
      a3 = fmaf(readlane_f(ue, k + 3), relc[(k + 3) * 65], a3);
    }
    t = (a0 + a1) + (a2 + a3);
  }

  // ---- softmaxes: score = bpermute lookup of t; 8-lane groups {1,2,4} ----
  float w2v;   // hop-2 weight for pair (m = ln>>3, n = ln&7)
  {
    const float s2 = __shfl(t, r2v, 64);
    float mx = s2;
    #pragma unroll
    for (int m = 1; m <= 4; m <<= 1) mx = fmaxf(mx, __shfl_xor(mx, m, 64));
    const float e = __expf(s2 - mx);
    float sm = e;
    #pragma unroll
    for (int m = 1; m <= 4; m <<= 1) sm += __shfl_xor(sm, m, 64);
    w2v = e / sm;
  }
  float w0v;   // hop-0 weight, valid on lanes 0..7 (reused for iter-1)
  {
    const float s0 = __shfl(t, r1v, 64);
    float mx = s0;
    #pragma unroll
    for (int m = 1; m <= 4; m <<= 1) mx = fmaxf(mx, __shfl_xor(mx, m, 64));
    w0v = __expf(s0 - mx);
    float sm = w0v;
    #pragma unroll
    for (int m = 1; m <= 4; m <<= 1) sm += __shfl_xor(sm, m, 64);
    w0v /= sm;
  }

  // ---- aggregation (lane = dim) ----
  {
    float agg = 0.f;
    #pragma unroll
    for (int n = 0; n < kNN; ++n)
      agg = fmaf(readlane_f(w0v, n), ev1r[n], agg);
    s_pre[wv][0][ln] = ev0 + agg;
  }
  // rows 1..8: gathers inline, unroll 2 (16 loads in flight; no prefetch
  // arrays -- R5 spill lesson).
  #pragma unroll 2
  for (int m = 0; m < kNN; ++m) {
    float acc = 0.f;
    #pragma unroll
    for (int n = 0; n < kNN; ++n) {
      const int e2u = __builtin_amdgcn_readlane(e2v, m * kNN + n);
      acc = fmaf(readlane_f(w2v, m * kNN + n),
                 ent_emb[(size_t)e2u * kDim + ln], acc);
    }
    s_pre[wv][1 + m][ln] = ev1r[m] + acc;
  }

  // ---- Wreg: ONE swizzled 16-read pass -> natural-order W[ln] row ----
  float4 Wreg[16];
  #pragma unroll
  for (int k4 = 0; k4 < 16; ++k4)
    Wreg[k4] = s_w4[(ln << 4) | (k4 & 8) | ((k4 ^ ln) & 7)];

  const float bln = bias[ln];

  // ---- 9 batched matvecs: p-reads are wave-uniform b128 broadcasts ----
  float h[kVecs];
  #pragma unroll
  for (int m = 0; m < kVecs; ++m) {
    const float* p0 = &s_pre[wv][m][0];
    float acc = 0.f;
    #pragma unroll
    for (int q = 0; q < 16; ++q) {
      const float4 p = *reinterpret_cast<const float4*>(p0 + (q << 2));
      acc = fmaf(Wreg[q].x, p.x, acc);
      acc = fmaf(Wreg[q].y, p.y, acc);
      acc = fmaf(Wreg[q].z, p.z, acc);
      acc = fmaf(Wreg[q].w, p.w, acc);
    }
    h[m] = fast_sigmoid(acc + bln);   // iter 0 -> sigmoid
  }

  // ---- iter-1 hop-0 (same ue, same rels -> reuse w0) ----
  {
    float pre = h[0];
    #pragma unroll
    for (int n = 0; n < kNN; ++n)
      pre = fmaf(readlane_f(w0v, n), h[1 + n], pre);
    s_pre[wv][0][ln] = pre;   // wave-internal DS ordering: no barrier needed
  }

  // ---- final matvec + tanh + user dot ----
  {
    const float* p0 = &s_pre[wv][0][0];
    float acc = 0.f;
    #pragma unroll
    for (int q = 0; q < 16; ++q) {
      const float4 p = *reinterpret_cast<const float4*>(p0 + (q << 2));
      acc = fmaf(Wreg[q].x, p.x, acc);
      acc = fmaf(Wreg[q].y, p.y, acc);
      acc = fmaf(Wreg[q].z, p.z, acc);
      acc = fmaf(Wreg[q].w, p.w, acc);
    }
    const float item = fast_tanh(acc + bln);
    float tt = ue * item;
    #pragma unroll
    for (int off = 32; off > 0; off >>= 1)
      tt += __shfl_xor(tt, off, 64);
    if (ln == 0) out[b] = fast_sigmoid(tt);
  }
}

}  // namespace

extern "C" void kernel_launch(void* const* d_in, const int* in_sizes, int n_in,
                              void* d_out, int out_size, void* d_ws, size_t ws_size,
                              hipStream_t stream) {
  const int*   u        = (const int*)d_in[0];
  const int*   v        = (const int*)d_in[1];
  const float* usr_emb  = (const float*)d_in[2];
  const float* item_emb = (const float*)d_in[3];
  const float* ent_emb  = (const float*)d_in[4];
  const float* rel_emb  = (const float*)d_in[5];
  const float* W        = (const float*)d_in[6];
  const float* bias     = (const float*)d_in[7];
  const int*   adj_ent  = (const int*)d_in[8];
  const int*   adj_rel  = (const int*)d_in[9];
  float*       out      = (float*)d_out;

  const int B = in_sizes[0];   // 16384, divisible by kElems=8
  dim3 grid(B / kElems), block(kElems * 64);
  hipLaunchKernelGGL(kgcn_kernel, grid, block, 0, stream,
                     u, v, usr_emb, item_emb, ent_emb, rel_emb, W, bias,
                     adj_ent, adj_rel, out);
}